// Round 7
// baseline (107.432 us; speedup 1.0000x reference)
//
#include <hip/hip_runtime.h>

#define BS 16
#define NN 50000
#define SEQ 9
#define IC 32
#define OC 32
#define FAN 320
#define GROUPS 64
#define MTILES_PER_B (NN / 16)          // 3125
#define TPX (2 * MTILES_PER_B)          // tiles per XCD (2 batches) = 6250
#define PPX (TPX / 2)                   // tile-pairs per XCD = 3125
#define KBLK 2048                       // kmfma blocks (4 waves each)
#define WPX (KBLK / 8 * 4)              // waves per XCD = 1024
#define WLN (SEQ * 2 * 64 * 4)          // wl uints (hi only) = 4608 -> 18432 B

typedef __attribute__((ext_vector_type(8))) short short8;
typedef __attribute__((ext_vector_type(4))) float f32x4;
typedef __attribute__((ext_vector_type(4))) unsigned uint32x4;

__device__ __forceinline__ float4 fmax4(float4 a, float4 b) {
  return make_float4(fmaxf(a.x, b.x), fmaxf(a.y, b.y), fmaxf(a.z, b.z), fmaxf(a.w, b.w));
}

// pack2: one uint = bf16 pair. A and B sides use the same pair-order ->
// any k-permutation cancels in the dot product.
__device__ __forceinline__ unsigned pk_bf16(float a, float b) {
  unsigned r;
  asm("v_cvt_pk_bf16_f32 %0, %1, %2" : "=v"(r) : "v"(a), "v"(b));
  return r;
}

__device__ __forceinline__ void split8(const float* v, unsigned* hi, unsigned* lo) {
#pragma unroll
  for (int i = 0; i < 4; i++) {
    float a = v[2 * i], b = v[2 * i + 1];
    unsigned h = pk_bf16(a, b);
    float fa = __builtin_bit_cast(float, h << 16);
    float fb = __builtin_bit_cast(float, h & 0xFFFF0000u);
    lo[i] = pk_bf16(a - fa, b - fb);
    hi[i] = h;
  }
}

union FragU { unsigned u[4]; short8 v; };

// ---------- Pass 1: column-max partials + fp32->bf16 convert ----------
// b = bg & 15  =>  batch b's blocks land on XCD b%8 (round-robin dispatch),
// matching kmfma_bf's reader XCD (which owns batches {x, x+8}).
__global__ __launch_bounds__(256) void kprep(const float* __restrict__ x,
                                             float* __restrict__ partial,
                                             unsigned* __restrict__ xh) {
  int bg = blockIdx.x;
  int b = bg & 15, g = bg >> 4;
  int t = threadIdx.x;
  int q = t & 7, r = t >> 3;
  const float4* xb = (const float4*)(x + (size_t)b * NN * IC);
  unsigned* xhb = xh ? xh + (size_t)b * NN * 16 : nullptr;
  float4 m = make_float4(-INFINITY, -INFINITY, -INFINITY, -INFINITY);
  for (int n = g * 32 + r; n < NN; n += GROUPS * 32) {
    float4 v = xb[n * 8 + q];
    m = fmax4(m, v);
    if (xhb) {
      uint2 p = make_uint2(pk_bf16(v.x, v.y), pk_bf16(v.z, v.w));
      *(uint2*)&xhb[n * 16 + q * 2] = p;
    }
  }
  __shared__ float4 sm[32][8];
  sm[r][q] = m;
  __syncthreads();
  for (int s = 16; s >= 1; s >>= 1) {
    if (r < s) sm[r][q] = fmax4(sm[r][q], sm[r + s][q]);
    __syncthreads();
  }
  if (t < 8) ((float4*)(partial + bg * IC))[t] = sm[0][t];
}

// ---------- Pass 2 (fused): blocks 0..15 finish max + fold gcontrib;
//                            blocks 16..20 convert W -> bf16 fragments ----------
// wfrag element (s,n,l,e):  o = n*16 + (l&15), k = s*32 + (l>>4)*8 + e
__global__ __launch_bounds__(256) void kfuse(const float* __restrict__ partial,
                                             const float* __restrict__ W,
                                             const float* __restrict__ bias,
                                             float* __restrict__ gcontrib,
                                             unsigned* __restrict__ wfrag) {
  int t = threadIdx.x;
  if (blockIdx.x < BS) {
    int b = blockIdx.x;
    __shared__ float gmax[IC];
    if (t < IC) {
      float m = -INFINITY;
      for (int g = 0; g < GROUPS; g++) m = fmaxf(m, partial[(g * 16 + b) * IC + t]);
      gmax[t] = m;
    }
    __syncthreads();
    if (t < OC) {
      float acc = bias[t];
#pragma unroll
      for (int c = 0; c < IC; c++) acc += gmax[c] * W[t * FAN + SEQ * IC + c];
      gcontrib[b * OC + t] = acc;
    }
  } else {
    int slot = (blockIdx.x - BS) * 256 + t;
    if (slot >= SEQ * 2 * 64) return;
    int s = slot >> 7, rem = slot & 127;
    int n = rem >> 6, l = rem & 63;
    int o = n * 16 + (l & 15);
    int k0 = s * 32 + (l >> 4) * 8;
    const float* p = W + o * FAN + k0;
#pragma unroll
    for (int i = 0; i < 4; i++)
      wfrag[slot * 4 + i] = pk_bf16(p[2 * i], p[2 * i + 1]);
  }
}

// ---------- Main: bf16 gather + MFMA, pair-unrolled, XCD-batch-coherent ----------
__global__ __launch_bounds__(256, 4) void kmfma_bf(const unsigned* __restrict__ xh,
                                                   const int* __restrict__ idx,
                                                   const float* __restrict__ gcontrib,
                                                   const unsigned* __restrict__ wfrag,
                                                   float* __restrict__ out) {
  __shared__ __align__(16) unsigned wl[WLN]; // 18432 B -> 8 blocks/CU
  int t = threadIdx.x;
  for (int i = t; i < WLN; i += 256) wl[i] = wfrag[i];
  __syncthreads();

  int bid = blockIdx.x;
  int xcd = bid & 7, slot = bid >> 3;
  int wid = t >> 6, l = t & 63;
  int ws = slot * 4 + wid;                   // 0..WPX-1
  int lane_lo = l & 15, kg = l >> 4;

  for (int p = ws; p < PPX; p += WPX) {
    int t0 = 2 * p, t1 = 2 * p + 1;
    int bl0 = t0 >= MTILES_PER_B, bl1 = t1 >= MTILES_PER_B;
    int loc0 = t0 - bl0 * MTILES_PER_B, loc1 = t1 - bl1 * MTILES_PER_B;
    int b0 = xcd + 8 * bl0, b1 = xcd + 8 * bl1;
    int nb0 = loc0 * 16, nb1 = loc1 * 16;
    const unsigned* xb0 = xh + (size_t)b0 * NN * 16;
    const unsigned* xb1 = xh + (size_t)b1 * NN * 16;

    int j0[SEQ], j1[SEQ];
    const int* ip0 = idx + (nb0 + lane_lo) * SEQ;
    const int* ip1 = idx + (nb1 + lane_lo) * SEQ;
#pragma unroll
    for (int s = 0; s < SEQ; s++) j0[s] = ip0[s];
#pragma unroll
    for (int s = 0; s < SEQ; s++) j1[s] = ip1[s];

    f32x4 acc00 = {0.f, 0.f, 0.f, 0.f};
    f32x4 acc01 = {0.f, 0.f, 0.f, 0.f};
    f32x4 acc10 = {0.f, 0.f, 0.f, 0.f};
    f32x4 acc11 = {0.f, 0.f, 0.f, 0.f};

#pragma unroll
    for (int s = 0; s < SEQ; s++) {
      uint32x4 r0 = *(const uint32x4*)(xb0 + (size_t)j0[s] * 16 + kg * 4);
      uint32x4 r1 = *(const uint32x4*)(xb1 + (size_t)j1[s] * 16 + kg * 4);
      short8 a0 = __builtin_bit_cast(short8, r0);
      short8 a1 = __builtin_bit_cast(short8, r1);
      short8 bh0 = *(const short8*)&wl[(s * 2 + 0) * 256 + (l << 2)];
      short8 bh1 = *(const short8*)&wl[(s * 2 + 1) * 256 + (l << 2)];
      acc00 = __builtin_amdgcn_mfma_f32_16x16x32_bf16(a0, bh0, acc00, 0, 0, 0);
      acc01 = __builtin_amdgcn_mfma_f32_16x16x32_bf16(a0, bh1, acc01, 0, 0, 0);
      acc10 = __builtin_amdgcn_mfma_f32_16x16x32_bf16(a1, bh0, acc10, 0, 0, 0);
      acc11 = __builtin_amdgcn_mfma_f32_16x16x32_bf16(a1, bh1, acc11, 0, 0, 0);
    }

    // D layout: col = lane&15, row = (lane>>4)*4 + reg  [m89-verified]
    float g00 = gcontrib[b0 * OC + lane_lo];
    float g01 = gcontrib[b0 * OC + 16 + lane_lo];
    float g10 = gcontrib[b1 * OC + lane_lo];
    float g11 = gcontrib[b1 * OC + 16 + lane_lo];
#pragma unroll
    for (int jj = 0; jj < 4; jj++) {
      size_t o0 = ((size_t)b0 * NN + nb0 + kg * 4 + jj) * OC;
      size_t o1 = ((size_t)b1 * NN + nb1 + kg * 4 + jj) * OC;
      __builtin_nontemporal_store(acc00[jj] + g00, &out[o0 + lane_lo]);
      __builtin_nontemporal_store(acc01[jj] + g01, &out[o0 + 16 + lane_lo]);
      __builtin_nontemporal_store(acc10[jj] + g10, &out[o1 + lane_lo]);
      __builtin_nontemporal_store(acc11[jj] + g11, &out[o1 + 16 + lane_lo]);
    }
  }
}

// ---------- Fallback main (small ws): fp32 gather + split-A ----------
__global__ __launch_bounds__(256, 8) void kmfma_f32(const float* __restrict__ x,
                                                    const int* __restrict__ idx,
                                                    const float* __restrict__ gcontrib,
                                                    const unsigned* __restrict__ wfrag,
                                                    float* __restrict__ out) {
  __shared__ __align__(16) unsigned wl[WLN];
  int t = threadIdx.x;
  for (int i = t; i < WLN; i += 256) wl[i] = wfrag[i];
  __syncthreads();

  int bid = blockIdx.x;
  int xcd = bid & 7, slot = bid >> 3;
  int wid = t >> 6, l = t & 63;
  int ws = slot * 4 + wid;
  int lane_lo = l & 15, kg = l >> 4;

  for (int tt = ws; tt < TPX; tt += WPX) {
    int bloc = tt >= MTILES_PER_B;
    int loc = tt - bloc * MTILES_PER_B;
    int b = xcd + 8 * bloc;
    int nb = loc * 16;
    const float* xb = x + (size_t)b * NN * IC;

    int j[SEQ];
    const int* ip = idx + (nb + lane_lo) * SEQ;
#pragma unroll
    for (int s = 0; s < SEQ; s++) j[s] = ip[s];

    f32x4 acc0 = {0.f, 0.f, 0.f, 0.f};
    f32x4 acc1 = {0.f, 0.f, 0.f, 0.f};
#pragma unroll
    for (int s = 0; s < SEQ; s++) {
      const float4* row = (const float4*)(xb + (size_t)j[s] * IC + kg * 8);
      float4 q0 = row[0], q1 = row[1];
      float v[8] = {q0.x, q0.y, q0.z, q0.w, q1.x, q1.y, q1.z, q1.w};
      FragU ah, al;
      split8(v, ah.u, al.u);
      short8 bh0 = *(const short8*)&wl[(s * 2 + 0) * 256 + (l << 2)];
      short8 bh1 = *(const short8*)&wl[(s * 2 + 1) * 256 + (l << 2)];
      acc0 = __builtin_amdgcn_mfma_f32_16x16x32_bf16(ah.v, bh0, acc0, 0, 0, 0);
      acc0 = __builtin_amdgcn_mfma_f32_16x16x32_bf16(al.v, bh0, acc0, 0, 0, 0);
      acc1 = __builtin_amdgcn_mfma_f32_16x16x32_bf16(ah.v, bh1, acc1, 0, 0, 0);
      acc1 = __builtin_amdgcn_mfma_f32_16x16x32_bf16(al.v, bh1, acc1, 0, 0, 0);
    }

    float g0 = gcontrib[b * OC + lane_lo];
    float g1 = gcontrib[b * OC + 16 + lane_lo];
#pragma unroll
    for (int jj = 0; jj < 4; jj++) {
      size_t o = ((size_t)b * NN + nb + kg * 4 + jj) * OC;
      __builtin_nontemporal_store(acc0[jj] + g0, &out[o + lane_lo]);
      __builtin_nontemporal_store(acc1[jj] + g1, &out[o + 16 + lane_lo]);
    }
  }
}

extern "C" void kernel_launch(void* const* d_in, const int* in_sizes, int n_in,
                              void* d_out, int out_size, void* d_ws, size_t ws_size,
                              hipStream_t stream) {
  const float* x = (const float*)d_in[0];
  const int* idx = (const int*)d_in[1];
  const float* W = (const float*)d_in[2];
  const float* bias = (const float*)d_in[3];
  float* out = (float*)d_out;

  const size_t xh_bytes = (size_t)BS * NN * 16 * sizeof(unsigned); // 51.2 MB
  const size_t tail = (size_t)(BS * GROUPS * IC + BS * OC) * 4 + WLN * 4 + 1024;
  bool big = ws_size >= xh_bytes + tail;

  if (big) {
    unsigned* xh = (unsigned*)d_ws;
    float* partial = (float*)((char*)d_ws + xh_bytes);
    float* gcontrib = partial + BS * GROUPS * IC;
    unsigned* wfrag = (unsigned*)(gcontrib + BS * OC);
    kprep<<<BS * GROUPS, 256, 0, stream>>>(x, partial, xh);
    kfuse<<<BS + 5, 256, 0, stream>>>(partial, W, bias, gcontrib, wfrag);
    kmfma_bf<<<KBLK, 256, 0, stream>>>(xh, idx, gcontrib, wfrag, out);
  } else {
    float* partial = (float*)d_ws;
    float* gcontrib = partial + BS * GROUPS * IC;
    unsigned* wfrag = (unsigned*)(gcontrib + BS * OC);
    kprep<<<BS * GROUPS, 256, 0, stream>>>(x, partial, nullptr);
    kfuse<<<BS + 5, 256, 0, stream>>>(partial, W, bias, gcontrib, wfrag);
    kmfma_f32<<<KBLK, 256, 0, stream>>>(x, idx, gcontrib, wfrag, out);
  }
}